// Round 20
// baseline (3406.429 us; speedup 1.0000x reference)
//
#include <hip/hip_runtime.h>

#define Bb 32
#define Tt 512
#define Ee 512
#define Hh 1024

typedef __attribute__((ext_vector_type(8))) short bf16x8;
typedef __attribute__((ext_vector_type(4))) float f32x4;
typedef __attribute__((ext_vector_type(4))) unsigned u32x4;
typedef unsigned long long u64;

#define SEN 0x7FC0u   // bf16 NaN; f2bf(finite h) can never produce it

__device__ __forceinline__ unsigned short f2bf(float f) {
  unsigned int u = __float_as_uint(f);
  u = (u + 0x7fffu + ((u >> 16) & 1u)) >> 16;
  return (unsigned short)u;
}
__device__ __forceinline__ float sigmoidf_(float x) {
  x = fminf(fmaxf(x, -30.f), 30.f);
  return 1.f / (1.f + __expf(-x));
}
__device__ __forceinline__ float tanh_fast(float x) {
  float xx = fminf(fmaxf(x, -15.f), 15.f);
  float e = __expf(2.f * xx);
  return (e - 1.f) / (e + 1.f);
}
__device__ __forceinline__ bool frag_bad(u32x4 v) {
  return ((v[0] & 0xFFFFu) == SEN) | ((v[1] & 0xFFFFu) == SEN) |
         ((v[2] & 0xFFFFu) == SEN) | ((v[3] & 0xFFFFu) == SEN);
}

// K1: gather emb -> bf16; ring slot0 zeros, slots 1..511 sentinel;
// optionally pre-convert W_ih -> bf16 (wih_flag != 0).
__global__ void gather_kernel(const int* __restrict__ x,
                              const float* __restrict__ emb,
                              unsigned short* __restrict__ emb_hi,
                              unsigned short* __restrict__ hbuf,
                              unsigned short* __restrict__ wih_bf,
                              int wih_flag) {
  long long gid = (long long)blockIdx.x * blockDim.x + threadIdx.x;
  long long stride = (long long)gridDim.x * blockDim.x;
  for (long long i = gid; i < 8192; i += stride)
    ((ushort4*)hbuf)[i] = make_ushort4(0, 0, 0, 0);
  for (long long i = 8192 + gid; i < 4194304; i += stride)
    ((ushort4*)hbuf)[i] =
        make_ushort4((unsigned short)SEN, (unsigned short)SEN,
                     (unsigned short)SEN, (unsigned short)SEN);
  long long n4 = (long long)Bb * Tt * Ee / 4;
  for (long long i = gid; i < n4; i += stride) {
    long long bt = i >> 7;
    int e4 = (int)(i & 127);
    int row = x[bt];
    row = min(max(row, 0), 31999);
    float4 v = ((const float4*)(emb + (long long)row * Ee))[e4];
    ushort4 hv;
    hv.x = f2bf(v.x); hv.y = f2bf(v.y);
    hv.z = f2bf(v.z); hv.w = f2bf(v.w);
    ((ushort4*)emb_hi)[i] = hv;
  }
  if (wih_flag) {
    // wih source: reuse emb pointer arg? No — W_ih passed via emb? Separate:
  }
}

// K1b: W_ih f32 -> bf16 flat (only launched when ws has room).
__global__ void wconv_kernel(const float* __restrict__ W_ih,
                             unsigned short* __restrict__ wih_bf) {
  long long gid = (long long)blockIdx.x * blockDim.x + threadIdx.x;
  long long stride = (long long)gridDim.x * blockDim.x;
  for (long long i = gid; i < 524288; i += stride) {   // 2M elems / 4
    float4 v = ((const float4*)W_ih)[i];
    ushort4 hv;
    hv.x = f2bf(v.x); hv.y = f2bf(v.y);
    hv.z = f2bf(v.z); hv.w = f2bf(v.w);
    ((ushort4*)wih_bf)[i] = hv;
  }
}

// K2: persistent LSTM, 64 FAT WGs x 4 waves. WG owns 16 units j0..j0+15
// (64 gate rows), j0 = (wg&7)*128 + (wg>>3)*16. Waves (kw,mt) K-split-2.
// W_hh slice (128 KB) in LDS; W_ih B-frags from GLOBAL bf16 (L2-resident,
// loads issue in the pre-wait shadow). Broadcast = 64 x 64 KB = 4 MB/step.
// Pure dataflow (R16/R19-proven): sentinel ring, plain burst + per-fragment
// sc1 spin, fire-and-forget sc1 publish. sAcc single-buffer + tail barrier.
template <bool PRE>
__global__ __launch_bounds__(256, 1)
void lstm_kernel(const unsigned short* __restrict__ emb_hi,
                 unsigned short* __restrict__ hbuf,
                 const unsigned short* __restrict__ wih_bf,
                 const float* __restrict__ W_ih,
                 const float* __restrict__ W_hh,
                 const float* __restrict__ b_ih,
                 const float* __restrict__ b_hh,
                 float* __restrict__ out) {
  __shared__ unsigned short sWhh[64 * 1024];        // 128 KB
  __shared__ float sAcc[2][2][4][16][17];           // [kw][mt][g][r][c] 17.4 KB

  const int tid = threadIdx.x;
  const int lane = tid & 63;
  const int wv = tid >> 6;
  const int wg = blockIdx.x;
  const int j0 = (wg & 7) * 128 + (wg >> 3) * 16;   // 16 units per WG

  // ---- stage W_hh slice (64 rows x 1024) bf16, XOR-swizzled ----
  for (int idx = tid; idx < 64 * 128; idx += 256) {
    int c = idx >> 7, k8 = idx & 127;
    int grow = (c >> 4) * Hh + j0 + (c & 15);
    const float* src = W_hh + (long long)grow * Hh + k8 * 8;
    int us = (c * 1024 + k8 * 8) ^ ((c & 7) << 3);
#pragma unroll
    for (int j = 0; j < 8; j++) sWhh[us + j] = f2bf(src[j]);
  }

  // ---- per-thread bias (gates x {u, u+8}) and c-state in registers ----
  const int bb = tid >> 3, uu = tid & 7;
  float bias[4][2];
#pragma unroll
  for (int g = 0; g < 4; g++) {
    bias[g][0] = b_ih[g * Hh + j0 + uu] + b_hh[g * Hh + j0 + uu];
    bias[g][1] = b_ih[g * Hh + j0 + 8 + uu] + b_hh[g * Hh + j0 + 8 + uu];
  }
  float c0 = 0.f, c1 = 0.f;
  float hL0 = 0.f, hL1 = 0.f, cL0 = 0.f, cL1 = 0.f;
  __syncthreads();

  const int r16 = lane & 15;        // A-frag row (batch within tile)
  const int kg = (lane >> 4) * 8;   // k-offset in 32-chunk
  const int col = lane & 15;        // B-frag col = unit
  const int kw = wv & 1;            // K-split half
  const int mt = wv >> 1;           // batch tile
  const int rb = mt * 16 + r16;     // global batch row

  for (int t = 0; t < Tt; t++) {
    __builtin_amdgcn_sched_barrier(0);

    // ---- burst: 16 plain dwordx4 h loads (this wave's mt, K-half kw) ----
    const u32x4* hb4 = (const u32x4*)(hbuf + (u64)t * 32768);
    const u64* hb8 = (const u64*)(hbuf + (u64)t * 32768);
    u32x4 hA[16];
    int iA[16];
#pragma unroll
    for (int q = 0; q < 16; q++) {
      int kc = q * 2 + kw;
      iA[q] = (rb * Hh + kc * 32 + kg) >> 3;
      hA[q] = hb4[iA[q]];
    }

    // ---- x_proj: A from emb (global), B from W_ih (global, L2-resident) --
    f32x4 acc[4];
#pragma unroll
    for (int g = 0; g < 4; g++) acc[g] = (f32x4){0.f, 0.f, 0.f, 0.f};
#pragma unroll
    for (int q = 0; q < 8; q++) {
      int kc = q * 2 + kw;
      int ai = (rb * Tt + t) * Ee + kc * 32 + kg;
      bf16x8 aH = *(const bf16x8*)(emb_hi + ai);
#pragma unroll
      for (int g = 0; g < 4; g++) {
        long long grow = (long long)(g * Hh + j0 + col);
        bf16x8 bW;
        if constexpr (PRE) {
          bW = *(const bf16x8*)(wih_bf + grow * Ee + kc * 32 + kg);
        } else {
          const float* wp = W_ih + grow * Ee + kc * 32 + kg;
          float4 w0 = *(const float4*)wp;
          float4 w1 = *(const float4*)(wp + 4);
          unsigned p0, p1, p2, p3;
          asm("v_cvt_pk_bf16_f32 %0, %1, %2" : "=v"(p0) : "v"(w0.x), "v"(w0.y));
          asm("v_cvt_pk_bf16_f32 %0, %1, %2" : "=v"(p1) : "v"(w0.z), "v"(w0.w));
          asm("v_cvt_pk_bf16_f32 %0, %1, %2" : "=v"(p2) : "v"(w1.x), "v"(w1.y));
          asm("v_cvt_pk_bf16_f32 %0, %1, %2" : "=v"(p3) : "v"(w1.z), "v"(w1.w));
          union { unsigned u[4]; bf16x8 v; } uw;
          uw.u[0] = p0; uw.u[1] = p1; uw.u[2] = p2; uw.u[3] = p3;
          bW = uw.v;
        }
        acc[g] = __builtin_amdgcn_mfma_f32_16x16x32_bf16(aH, bW, acc[g], 0, 0, 0);
      }
    }

    // ---- validate per fragment (sc1 spin) + recurrent MFMAs ----
#pragma unroll
    for (int q = 0; q < 16; q++) {
      int kc = q * 2 + kw;
      u32x4 va = hA[q];
      bool bad = frag_bad(va);
      while (__any(bad)) {
        if (bad) {
          u64 a0 = __hip_atomic_load(hb8 + iA[q] * 2, __ATOMIC_RELAXED,
                                     __HIP_MEMORY_SCOPE_AGENT);
          u64 a1 = __hip_atomic_load(hb8 + iA[q] * 2 + 1, __ATOMIC_RELAXED,
                                     __HIP_MEMORY_SCOPE_AGENT);
          va[0] = (unsigned)a0; va[1] = (unsigned)(a0 >> 32);
          va[2] = (unsigned)a1; va[3] = (unsigned)(a1 >> 32);
        }
        bad = frag_bad(va);
      }
      union { u32x4 u; bf16x8 v; } ua;
      ua.u = va;
#pragma unroll
      for (int g = 0; g < 4; g++) {
        int c = g * 16 + col;
        int bo = (c * 1024 + kc * 32 + kg) ^ ((c & 7) << 3);
        bf16x8 bW = *(const bf16x8*)(sWhh + bo);
        acc[g] = __builtin_amdgcn_mfma_f32_16x16x32_bf16(ua.v, bW, acc[g], 0, 0, 0);
      }
    }

    // ---- K-split reduce via LDS (single buffer) ----
#pragma unroll
    for (int g = 0; g < 4; g++)
#pragma unroll
      for (int r = 0; r < 4; r++)
        sAcc[kw][mt][g][(lane >> 4) * 4 + r][col] = acc[g][r];
    __syncthreads();

    // ---- cell: 256 threads x 2 units (uu, uu+8) ----
    {
      int mtc = bb >> 4, rr = bb & 15;
#pragma unroll
      for (int half = 0; half < 2; half++) {
        int ui = uu + half * 8;
        float g0 = sAcc[0][mtc][0][rr][ui] + sAcc[1][mtc][0][rr][ui] + bias[0][half];
        float g1 = sAcc[0][mtc][1][rr][ui] + sAcc[1][mtc][1][rr][ui] + bias[1][half];
        float g2 = sAcc[0][mtc][2][rr][ui] + sAcc[1][mtc][2][rr][ui] + bias[2][half];
        float g3 = sAcc[0][mtc][3][rr][ui] + sAcc[1][mtc][3][rr][ui] + bias[3][half];
        float ig = sigmoidf_(g0);
        float fg = sigmoidf_(g1);
        float gg = tanh_fast(g2);
        float og = sigmoidf_(g3);
        float cp = half ? c1 : c0;
        float cn = fg * cp + ig * gg;
        if (half) c1 = cn; else c0 = cn;
        float hn = og * tanh_fast(cn);
        if (half) { hL1 = hn; cL1 = cn; } else { hL0 = hn; cL0 = cn; }

        // publish h[t+1]: fire-and-forget u32 sc1 stores (pair via shfl)
        unsigned pack = (unsigned)f2bf(hn);
        unsigned other = __shfl_xor(pack, 1, 64);
        if (t + 1 < Tt && (uu & 1) == 0) {
          unsigned w = (pack & 0xffffu) | (other << 16);
          unsigned* nb32 = (unsigned*)(hbuf + (u64)(t + 1) * 32768);
          __hip_atomic_store(nb32 + ((bb * Hh + j0 + ui) >> 1), w,
                             __ATOMIC_RELAXED, __HIP_MEMORY_SCOPE_AGENT);
        }
        out[((long long)bb * Tt + t) * Hh + j0 + ui] = hn;
      }
    }
    __syncthreads();   // tail: protect single-buffered sAcc
  }

  out[16777216LL + bb * Hh + j0 + uu] = hL0;             // state_h
  out[16777216LL + bb * Hh + j0 + 8 + uu] = hL1;
  out[16777216LL + 32768 + bb * Hh + j0 + uu] = cL0;     // state_c
  out[16777216LL + 32768 + bb * Hh + j0 + 8 + uu] = cL1;
}

extern "C" void kernel_launch(void* const* d_in, const int* in_sizes, int n_in,
                              void* d_out, int out_size, void* d_ws, size_t ws_size,
                              hipStream_t stream) {
  const int* x      = (const int*)d_in[0];
  const float* emb  = (const float*)d_in[1];
  const float* W_ih = (const float*)d_in[2];
  const float* W_hh = (const float*)d_in[3];
  const float* b_ih = (const float*)d_in[4];
  const float* b_hh = (const float*)d_in[5];
  float* out = (float*)d_out;

  unsigned short* emb_hi = (unsigned short*)d_ws;      // 16 MB
  unsigned short* hbuf   = emb_hi + 8388608;           // 512-slot ring, 32 MB
  unsigned short* wih_bf = hbuf + 16777216;            // 4 MB (if ws allows)

  bool pre = (ws_size >= 54525952ull);                 // 52 MB

  hipLaunchKernelGGL(gather_kernel, dim3(2048), dim3(256), 0, stream,
                     x, emb, emb_hi, hbuf, wih_bf, 0);
  if (pre)
    hipLaunchKernelGGL(wconv_kernel, dim3(512), dim3(256), 0, stream,
                       W_ih, wih_bf);

  void* args[] = { (void*)&emb_hi, (void*)&hbuf, (void*)&wih_bf, (void*)&W_ih,
                   (void*)&W_hh, (void*)&b_ih, (void*)&b_hh, (void*)&out };
  if (pre) {
    hipError_t e = hipLaunchCooperativeKernel((void*)lstm_kernel<true>,
                                              dim3(64), dim3(256), args, 0, stream);
    if (e != hipSuccess)
      hipLaunchKernelGGL(lstm_kernel<true>, dim3(64), dim3(256), 0, stream,
                         emb_hi, hbuf, wih_bf, W_ih, W_hh, b_ih, b_hh, out);
  } else {
    hipError_t e = hipLaunchCooperativeKernel((void*)lstm_kernel<false>,
                                              dim3(64), dim3(256), args, 0, stream);
    if (e != hipSuccess)
      hipLaunchKernelGGL(lstm_kernel<false>, dim3(64), dim3(256), 0, stream,
                         emb_hi, hbuf, wih_bf, W_ih, W_hh, b_ih, b_hh, out);
  }
}